// Round 10
// baseline (151.856 us; speedup 1.0000x reference)
//
#include <hip/hip_runtime.h>

#define SDIM 2048
#define NHEADS 16
#define HD 64

typedef __attribute__((ext_vector_type(8))) short bf16x8;
typedef __attribute__((ext_vector_type(8))) unsigned short u16x8;
typedef __attribute__((ext_vector_type(4))) float f32x4;
typedef unsigned short u16;

static __device__ __forceinline__ u16 f2bf(float f) {
  unsigned u = __builtin_bit_cast(unsigned, f);
  u += 0x7fffu + ((u >> 16) & 1u);   // RNE
  return (u16)(u >> 16);
}

// pack two f32 -> two bf16 in one instruction (no builtin on gfx950)
static __device__ __forceinline__ unsigned cvt_pk_bf16(float lo, float hi) {
  unsigned r;
  asm("v_cvt_pk_bf16_f32 %0, %1, %2" : "=v"(r) : "v"(lo), "v"(hi));
  return r;
}

static __device__ __forceinline__ f32x4 mfma16(bf16x8 a, bf16x8 b, f32x4 c) {
  return __builtin_amdgcn_mfma_f32_16x16x32_bf16(a, b, c, 0, 0, 0);
}

// async global->LDS, 16B per lane; LDS dest is wave-uniform base + lane*16
static __device__ __forceinline__ void gload16(const u16* g, u16* l) {
  __builtin_amdgcn_global_load_lds(
      (const __attribute__((address_space(1))) void*)g,
      (__attribute__((address_space(3))) void*)l, 16, 0, 0);
}

// ---------- prep: fp32 -> bf16, 8 elems/thread ----------
__global__ void cvt_kernel(const float* __restrict__ in, u16* __restrict__ out, int n8) {
  int i = blockIdx.x * blockDim.x + threadIdx.x;
  if (i >= n8) return;
  const float4* p = (const float4*)(in + (long)i * 8);
  float4 a = p[0], b = p[1];
  u16x8 r;
  r[0] = f2bf(a.x); r[1] = f2bf(a.y); r[2] = f2bf(a.z); r[3] = f2bf(a.w);
  r[4] = f2bf(b.x); r[5] = f2bf(b.y); r[6] = f2bf(b.z); r[7] = f2bf(b.w);
  *(u16x8*)(out + (long)i * 8) = r;
}

// ---------- prep: W [K][N] fp32 -> Wt [N][K] bf16 ----------
__global__ void transpose_cvt(const float* __restrict__ W, u16* __restrict__ Wt, int K, int N) {
  __shared__ float t[32][33];
  int tx = threadIdx.x & 31, ty = threadIdx.x >> 5;   // 32 x 8
  int n0 = blockIdx.x * 32, k0 = blockIdx.y * 32;
#pragma unroll
  for (int i = 0; i < 32; i += 8) t[ty + i][tx] = W[(long)(k0 + ty + i) * N + n0 + tx];
  __syncthreads();
#pragma unroll
  for (int i = 0; i < 32; i += 8) Wt[(long)(n0 + ty + i) * K + k0 + tx] = f2bf(t[tx][ty + i]);
}

// ---------- V part of QKV [4096][3072] -> Vt [32][64][2048] bf16 ----------
__global__ __launch_bounds__(256) void vtrans_kernel(const u16* __restrict__ QKV,
                                                     u16* __restrict__ Vt) {
  __shared__ u16 t[64][72];
  const int bh = blockIdx.y, s0 = blockIdx.x * 64;
  const int b = bh >> 4, h = bh & 15;
  const u16* src = QKV + ((long)(b * SDIM + s0)) * 3072 + h * 192 + 128;
  int r = threadIdx.x >> 3, c = (threadIdx.x & 7) * 8;
  *(uint4*)&t[r][c]      = *(const uint4*)(src + (long)r * 3072 + c);
  *(uint4*)&t[r + 32][c] = *(const uint4*)(src + (long)(r + 32) * 3072 + c);
  __syncthreads();
  int d = threadIdx.x >> 2, sc = (threadIdx.x & 3) * 16;
  u16 tmp[16];
#pragma unroll
  for (int k = 0; k < 16; ++k) tmp[k] = t[sc + k][d];
  u16* dst = Vt + ((long)(bh * HD + d)) * SDIM + s0 + sc;
  *(uint4*)dst = *(uint4*)&tmp[0];
  *(uint4*)(dst + 8) = *(uint4*)&tmp[8];
}

// ---------- bf16 GEMM, 128x128x64 tile, 4 waves, global_load_lds staging ----------
// 1-D grid with bijective XCD swizzle (grid % 8 == 0).
template <int EPI>
__global__ __launch_bounds__(256) void gemm_bf16(
    const u16* __restrict__ A, const u16* __restrict__ Bt,
    const float* __restrict__ bias, float* __restrict__ Cf, u16* __restrict__ Cb,
    int M, int N, int K)
{
  __shared__ __align__(16) u16 As[128 * 64];
  __shared__ __align__(16) u16 Bs[128 * 64];
  const int tid = threadIdx.x, lane = tid & 63, wid = tid >> 6;
  const int wm = wid >> 1, wn = wid & 1;
  const int l15 = lane & 15, l4 = lane >> 4;
  const int nblk = gridDim.x;
  const int lb = (blockIdx.x & 7) * (nblk >> 3) + (blockIdx.x >> 3);  // XCD-chunked
  const int nx = N >> 7;
  const int m0 = (lb / nx) * 128, n0 = (lb % nx) * 128;
  const int srow = lane >> 3;
  const int schunk = (lane & 7) ^ srow;

  f32x4 acc[4][4];
#pragma unroll
  for (int i = 0; i < 4; ++i)
#pragma unroll
    for (int j = 0; j < 4; ++j) acc[i][j] = {0.f, 0.f, 0.f, 0.f};

  const int nk = K >> 6;
  for (int kt = 0; kt < nk; ++kt) {
    const int kc = kt << 6;
#pragma unroll
    for (int is = 0; is < 4; ++is) {
      int rb = wid * 32 + is * 8;
      int r = rb + srow;
      gload16(A  + (long)(m0 + r) * K + kc + schunk * 8, &As[rb * 64]);
      gload16(Bt + (long)(n0 + r) * K + kc + schunk * 8, &Bs[rb * 64]);
    }
    asm volatile("s_waitcnt vmcnt(0)" ::: "memory");
    __syncthreads();
#pragma unroll
    for (int kk = 0; kk < 2; ++kk) {
      bf16x8 af[4], bfr[4];
#pragma unroll
      for (int mt = 0; mt < 4; ++mt) {
        int row = wm * 64 + mt * 16 + l15;
        af[mt] = *(const bf16x8*)&As[row * 64 + (((kk * 4 + l4) ^ (l15 & 7)) * 8)];
      }
#pragma unroll
      for (int nt = 0; nt < 4; ++nt) {
        int row = wn * 64 + nt * 16 + l15;
        bfr[nt] = *(const bf16x8*)&Bs[row * 64 + (((kk * 4 + l4) ^ (l15 & 7)) * 8)];
      }
#pragma unroll
      for (int mt = 0; mt < 4; ++mt)
#pragma unroll
        for (int nt = 0; nt < 4; ++nt)
          acc[mt][nt] = mfma16(af[mt], bfr[nt], acc[mt][nt]);
    }
    __syncthreads();
  }

#pragma unroll
  for (int mt = 0; mt < 4; ++mt)
#pragma unroll
    for (int nt = 0; nt < 4; ++nt)
#pragma unroll
      for (int r = 0; r < 4; ++r) {
        int row = m0 + wm * 64 + mt * 16 + l4 * 4 + r;
        int col = n0 + wn * 64 + nt * 16 + l15;
        float v = acc[mt][nt][r] + bias[col];
        if (EPI == 0) Cf[(long)row * N + col] = v;
        else          Cb[(long)row * N + col] = f2bf(v);
      }
}

// ---------- flash attention: 4 waves (256 thr), QBLK=64, KBLK=64 ----------
// Same per-wave work/fragments as r9's waves 0-3; grid 512->1024 (4 blocks/CU)
// to overlap barrier stalls across independent blocks. LDS 40 KB (4/CU exact).
__global__ __launch_bounds__(256) void attn_kernel(
    const u16* __restrict__ QKV, const u16* __restrict__ Vtg,
    const int* __restrict__ maskg, u16* __restrict__ Og)
{
  __shared__ __align__(16) u16 Ks[2][64][64];   // 16 KB
  __shared__ __align__(16) u16 Vs[2][64][64];   // 16 KB
  __shared__ __align__(16) u16 Ps[64][64];      //  8 KB
  const int tid = threadIdx.x, lane = tid & 63, w = tid >> 6;   // w in 0..3
  const int l15 = lane & 15, l4 = lane >> 4;
  // XCD swizzle: 1024 blocks -> 128/XCD = 4 heads x 32 q-tiles (K/V set 2MB < L2)
  const int lb = (blockIdx.x & 7) * 128 + (blockIdx.x >> 3);
  const int qt = lb & 31, bh = lb >> 5;
  const int b = bh >> 4, h = bh & 15;
  const u16* Qp = QKV + ((long)(b * SDIM + qt * 64)) * 3072 + h * 192;
  const u16* Kp = QKV + (long)(b * SDIM) * 3072 + h * 192 + 64;
  const u16* Vp = Vtg + (long)bh * HD * SDIM;
  const float SC = 0.18033688011112042f;   // log2(e) / sqrt(64)
  const int NT = SDIM / 64;                // 32

  bf16x8 qa[2];
#pragma unroll
  for (int ks = 0; ks < 2; ++ks)
    qa[ks] = *(const bf16x8*)(Qp + (long)(w * 16 + l15) * 3072 + ks * 32 + l4 * 8);

  f32x4 O[4];
  float lsum[4];
#pragma unroll
  for (int dt = 0; dt < 4; ++dt) O[dt] = {0.f, 0.f, 0.f, 0.f};
#pragma unroll
  for (int r = 0; r < 4; ++r) lsum[r] = 0.f;

  char* KsB = (char*)&Ks[0][0][0];
  char* VsB = (char*)&Vs[0][0][0];
  char* PsB = (char*)&Ps[0][0];
  const int srow = lane >> 3;
  const int schunk = (lane & 7) ^ srow;

  // ---- hoisted addressing (all loop-invariant) ----
  // wave w stages rows [w*16, w*16+16): two 8-row groups per tensor
  u16* kDst[2][2] = { { (u16*)(KsB + w * 2048),        (u16*)(KsB + w * 2048 + 1024) },
                      { (u16*)(KsB + 8192 + w * 2048), (u16*)(KsB + 8192 + w * 2048 + 1024) } };
  u16* vDst[2][2] = { { (u16*)(VsB + w * 2048),        (u16*)(VsB + w * 2048 + 1024) },
                      { (u16*)(VsB + 8192 + w * 2048), (u16*)(VsB + 8192 + w * 2048 + 1024) } };
  const u16* kS0 = Kp + (long)(w * 16 + srow) * 3072 + schunk * 8;       // tile 0, group 0
  const u16* kS1 = Kp + (long)(w * 16 + 8 + srow) * 3072 + schunk * 8;   // group 1
  const u16* vS0 = Vp + (long)(w * 16 + srow) * SDIM + schunk * 8;
  const u16* vS1 = Vp + (long)(w * 16 + 8 + srow) * SDIM + schunk * 8;
  const int* mrow = maskg + b * SDIM + l15;

  int off[2][4];     // LDS read offsets for K and V rows (same pattern)
#pragma unroll
  for (int j = 0; j < 2; ++j)
#pragma unroll
    for (int x = 0; x < 4; ++x)
      off[j][x] = (x * 16 + l15) * 128 + (((j * 4 + l4) ^ (l15 & 7)) << 4);
  int poffr[2];      // P-read (A-fragment) offsets
#pragma unroll
  for (int j = 0; j < 2; ++j)
    poffr[j] = (w * 16 + l15) * 128 + (((j * 4 + l4) ^ (l15 & 7)) << 4);
  int pw[4][4];      // P-write offsets
#pragma unroll
  for (int r = 0; r < 4; ++r) {
    int prow = w * 16 + l4 * 4 + r, rx = prow & 7, ch = l15 >> 3;
    int rbase = prow * 128 + (l15 & 7) * 2;
#pragma unroll
    for (int c = 0; c < 4; ++c) pw[r][c] = rbase + (((2 * c + ch) ^ rx) << 4);
  }

  // prologue: stage tile 0, advance source pointers to tile 1
  gload16(kS0, kDst[0][0]); gload16(kS1, kDst[0][1]);
  gload16(vS0, vDst[0][0]); gload16(vS1, vDst[0][1]);
  kS0 += 64 * 3072; kS1 += 64 * 3072; vS0 += 64; vS1 += 64;
  asm volatile("s_waitcnt vmcnt(0)" ::: "memory");
  __syncthreads();

  for (int kt = 0; kt < NT; ++kt) {
    const int cur = kt & 1;
    if (kt + 1 < NT) {                      // DMA next tile under compute
      gload16(kS0, kDst[cur ^ 1][0]); gload16(kS1, kDst[cur ^ 1][1]);
      gload16(vS0, vDst[cur ^ 1][0]); gload16(vS1, vDst[cur ^ 1][1]);
      kS0 += 64 * 3072; kS1 += 64 * 3072; vS0 += 64; vS1 += 64;
    }

    float mbM[4];
#pragma unroll
    for (int nt = 0; nt < 4; ++nt)
      mbM[nt] = (mrow[nt * 16] ? 0.f : -1e30f) - 12.0f;   // mask bias - static max
    mrow += 64;

    const char* Kc = KsB + cur * 8192;
    const char* Vc = VsB + cur * 8192;

    // S = Q K^T (per wave: 16 x 64)
    f32x4 sc4[4];
    __builtin_amdgcn_s_setprio(1);
#pragma unroll
    for (int nt = 0; nt < 4; ++nt) {
      bf16x8 kb0 = *(const bf16x8*)(Kc + off[0][nt]);
      bf16x8 kb1 = *(const bf16x8*)(Kc + off[1][nt]);
      f32x4 z = {0.f, 0.f, 0.f, 0.f};
      z = mfma16(qa[0], kb0, z);
      z = mfma16(qa[1], kb1, z);
      sc4[nt] = z;
    }
    __builtin_amdgcn_s_setprio(0);

    // static-max softmax: P = exp2(s*SC + mb - 12); per-lane partial row-sum
#pragma unroll
    for (int r = 0; r < 4; ++r) {
      float p0 = __builtin_amdgcn_exp2f(sc4[0][r] * SC + mbM[0]);
      float p1 = __builtin_amdgcn_exp2f(sc4[1][r] * SC + mbM[1]);
      float p2 = __builtin_amdgcn_exp2f(sc4[2][r] * SC + mbM[2]);
      float p3 = __builtin_amdgcn_exp2f(sc4[3][r] * SC + mbM[3]);
      lsum[r] += (p0 + p1) + (p2 + p3);
      unsigned u01 = cvt_pk_bf16(p0, p1);
      unsigned u23 = cvt_pk_bf16(p2, p3);
      *(u16*)(PsB + pw[r][0]) = (u16)u01;
      *(u16*)(PsB + pw[r][1]) = (u16)(u01 >> 16);
      *(u16*)(PsB + pw[r][2]) = (u16)u23;
      *(u16*)(PsB + pw[r][3]) = (u16)(u23 >> 16);
    }
    // P consumed by the same wave only -> lgkmcnt drain, no barrier
    asm volatile("s_waitcnt lgkmcnt(0)" ::: "memory");
    __builtin_amdgcn_sched_barrier(0);

    // O += P V
    __builtin_amdgcn_s_setprio(1);
#pragma unroll
    for (int ks2 = 0; ks2 < 2; ++ks2) {
      bf16x8 pa = *(const bf16x8*)(PsB + poffr[ks2]);
#pragma unroll
      for (int dt = 0; dt < 4; ++dt) {
        bf16x8 vb = *(const bf16x8*)(Vc + off[ks2][dt]);
        O[dt] = mfma16(pa, vb, O[dt]);
      }
    }
    __builtin_amdgcn_s_setprio(0);
    __syncthreads();   // drains prefetch vmcnt + syncs buffers (one barrier per tile)
  }

  // one butterfly at the end recovers each row's denominator
  float inv[4];
#pragma unroll
  for (int r = 0; r < 4; ++r) {
    float s = lsum[r];
#pragma unroll
    for (int off2 = 1; off2 < 16; off2 <<= 1) s += __shfl_xor(s, off2);
    inv[r] = 1.0f / s;
  }

#pragma unroll
  for (int dt = 0; dt < 4; ++dt)
#pragma unroll
    for (int r = 0; r < 4; ++r) {
      int s = qt * 64 + w * 16 + l4 * 4 + r;
      int d = dt * 16 + l15;
      Og[((long)(b * SDIM + s)) * 1024 + h * HD + d] = f2bf(O[dt][r] * inv[r]);
    }
}

extern "C" void kernel_launch(void* const* d_in, const int* in_sizes, int n_in,
                              void* d_out, int out_size, void* d_ws, size_t ws_size,
                              hipStream_t stream) {
  const float* x    = (const float*)d_in[0];
  const int*   am   = (const int*)d_in[1];
  const float* Wqkv = (const float*)d_in[2];
  const float* bqkv = (const float*)d_in[3];
  const float* Wout = (const float*)d_in[4];
  const float* bout = (const float*)d_in[5];
  float* out = (float*)d_out;
  char* ws = (char*)d_ws;

  u16* xb   = (u16*)(ws);                             // 8 MB   x bf16 [4096][1024]
  u16* AOb  = (u16*)(ws);                             // reused after QKV gemm: attn out bf16
  u16* wqt  = (u16*)(ws + (size_t) 8 * 1024 * 1024);  // 6 MB   W_qkv^T bf16 [3072][1024]
  u16* wot  = (u16*)(ws + (size_t)14 * 1024 * 1024);  // 2 MB   W_out^T bf16 [1024][1024]
  u16* QKVb = (u16*)(ws + (size_t)16 * 1024 * 1024);  // 24 MB  qkv bf16 [4096][3072]
  u16* Vtb  = (u16*)(ws + (size_t)40 * 1024 * 1024);  // 8 MB   V^T bf16 [32][64][2048]

  cvt_kernel<<<2048, 256, 0, stream>>>(x, xb, 524288);
  transpose_cvt<<<dim3(96, 32), 256, 0, stream>>>(Wqkv, wqt, 1024, 3072);
  transpose_cvt<<<dim3(32, 32), 256, 0, stream>>>(Wout, wot, 1024, 1024);
  gemm_bf16<1><<<768, 256, 0, stream>>>(xb, wqt, bqkv, nullptr, QKVb,
                                        4096, 3072, 1024);
  vtrans_kernel<<<dim3(32, 32), 256, 0, stream>>>(QKVb, Vtb);
  attn_kernel<<<1024, 256, 0, stream>>>(QKVb, Vtb, am, AOb);
  gemm_bf16<0><<<256, 256, 0, stream>>>(AOb, wot, bout, out, nullptr,
                                        4096, 1024, 1024);
}

// Round 12
// 149.669 us; speedup vs baseline: 1.0146x; 1.0146x over previous
//
#include <hip/hip_runtime.h>

#define SDIM 2048
#define NHEADS 16
#define HD 64

typedef __attribute__((ext_vector_type(8))) short bf16x8;
typedef __attribute__((ext_vector_type(8))) unsigned short u16x8;
typedef __attribute__((ext_vector_type(4))) float f32x4;
typedef unsigned short u16;

static __device__ __forceinline__ u16 f2bf(float f) {
  unsigned u = __builtin_bit_cast(unsigned, f);
  u += 0x7fffu + ((u >> 16) & 1u);   // RNE
  return (u16)(u >> 16);
}

// pack two f32 -> two bf16 in one instruction (no builtin on gfx950)
static __device__ __forceinline__ unsigned cvt_pk_bf16(float lo, float hi) {
  unsigned r;
  asm("v_cvt_pk_bf16_f32 %0, %1, %2" : "=v"(r) : "v"(lo), "v"(hi));
  return r;
}

static __device__ __forceinline__ f32x4 mfma16(bf16x8 a, bf16x8 b, f32x4 c) {
  return __builtin_amdgcn_mfma_f32_16x16x32_bf16(a, b, c, 0, 0, 0);
}

// async global->LDS, 16B per lane; LDS dest is wave-uniform base + lane*16
static __device__ __forceinline__ void gload16(const u16* g, u16* l) {
  __builtin_amdgcn_global_load_lds(
      (const __attribute__((address_space(1))) void*)g,
      (__attribute__((address_space(3))) void*)l, 16, 0, 0);
}

// ---------- prep: fp32 -> bf16, 8 elems/thread ----------
__global__ void cvt_kernel(const float* __restrict__ in, u16* __restrict__ out, int n8) {
  int i = blockIdx.x * blockDim.x + threadIdx.x;
  if (i >= n8) return;
  const float4* p = (const float4*)(in + (long)i * 8);
  float4 a = p[0], b = p[1];
  u16x8 r;
  r[0] = f2bf(a.x); r[1] = f2bf(a.y); r[2] = f2bf(a.z); r[3] = f2bf(a.w);
  r[4] = f2bf(b.x); r[5] = f2bf(b.y); r[6] = f2bf(b.z); r[7] = f2bf(b.w);
  *(u16x8*)(out + (long)i * 8) = r;
}

// ---------- prep: W [K][N] fp32 -> Wt [N][K] bf16 ----------
__global__ void transpose_cvt(const float* __restrict__ W, u16* __restrict__ Wt, int K, int N) {
  __shared__ float t[32][33];
  int tx = threadIdx.x & 31, ty = threadIdx.x >> 5;   // 32 x 8
  int n0 = blockIdx.x * 32, k0 = blockIdx.y * 32;
#pragma unroll
  for (int i = 0; i < 32; i += 8) t[ty + i][tx] = W[(long)(k0 + ty + i) * N + n0 + tx];
  __syncthreads();
#pragma unroll
  for (int i = 0; i < 32; i += 8) Wt[(long)(n0 + ty + i) * K + k0 + tx] = f2bf(t[tx][ty + i]);
}

// ---------- V part of QKV [4096][3072] -> Vt [32][64][2048] bf16 ----------
__global__ __launch_bounds__(256) void vtrans_kernel(const u16* __restrict__ QKV,
                                                     u16* __restrict__ Vt) {
  __shared__ u16 t[64][72];
  const int bh = blockIdx.y, s0 = blockIdx.x * 64;
  const int b = bh >> 4, h = bh & 15;
  const u16* src = QKV + ((long)(b * SDIM + s0)) * 3072 + h * 192 + 128;
  int r = threadIdx.x >> 3, c = (threadIdx.x & 7) * 8;
  *(uint4*)&t[r][c]      = *(const uint4*)(src + (long)r * 3072 + c);
  *(uint4*)&t[r + 32][c] = *(const uint4*)(src + (long)(r + 32) * 3072 + c);
  __syncthreads();
  int d = threadIdx.x >> 2, sc = (threadIdx.x & 3) * 16;
  u16 tmp[16];
#pragma unroll
  for (int k = 0; k < 16; ++k) tmp[k] = t[sc + k][d];
  u16* dst = Vt + ((long)(bh * HD + d)) * SDIM + s0 + sc;
  *(uint4*)dst = *(uint4*)&tmp[0];
  *(uint4*)(dst + 8) = *(uint4*)&tmp[8];
}

// ---------- bf16 GEMM, 128x128x64 tile, 4 waves, global_load_lds staging ----------
// 1-D grid with bijective XCD swizzle (grid % 8 == 0).
template <int EPI>
__global__ __launch_bounds__(256) void gemm_bf16(
    const u16* __restrict__ A, const u16* __restrict__ Bt,
    const float* __restrict__ bias, float* __restrict__ Cf, u16* __restrict__ Cb,
    int M, int N, int K)
{
  __shared__ __align__(16) u16 As[128 * 64];
  __shared__ __align__(16) u16 Bs[128 * 64];
  const int tid = threadIdx.x, lane = tid & 63, wid = tid >> 6;
  const int wm = wid >> 1, wn = wid & 1;
  const int l15 = lane & 15, l4 = lane >> 4;
  const int nblk = gridDim.x;
  const int lb = (blockIdx.x & 7) * (nblk >> 3) + (blockIdx.x >> 3);  // XCD-chunked
  const int nx = N >> 7;
  const int m0 = (lb / nx) * 128, n0 = (lb % nx) * 128;
  const int srow = lane >> 3;
  const int schunk = (lane & 7) ^ srow;

  f32x4 acc[4][4];
#pragma unroll
  for (int i = 0; i < 4; ++i)
#pragma unroll
    for (int j = 0; j < 4; ++j) acc[i][j] = {0.f, 0.f, 0.f, 0.f};

  const int nk = K >> 6;
  for (int kt = 0; kt < nk; ++kt) {
    const int kc = kt << 6;
#pragma unroll
    for (int is = 0; is < 4; ++is) {
      int rb = wid * 32 + is * 8;
      int r = rb + srow;
      gload16(A  + (long)(m0 + r) * K + kc + schunk * 8, &As[rb * 64]);
      gload16(Bt + (long)(n0 + r) * K + kc + schunk * 8, &Bs[rb * 64]);
    }
    asm volatile("s_waitcnt vmcnt(0)" ::: "memory");
    __syncthreads();
#pragma unroll
    for (int kk = 0; kk < 2; ++kk) {
      bf16x8 af[4], bfr[4];
#pragma unroll
      for (int mt = 0; mt < 4; ++mt) {
        int row = wm * 64 + mt * 16 + l15;
        af[mt] = *(const bf16x8*)&As[row * 64 + (((kk * 4 + l4) ^ (l15 & 7)) * 8)];
      }
#pragma unroll
      for (int nt = 0; nt < 4; ++nt) {
        int row = wn * 64 + nt * 16 + l15;
        bfr[nt] = *(const bf16x8*)&Bs[row * 64 + (((kk * 4 + l4) ^ (l15 & 7)) * 8)];
      }
#pragma unroll
      for (int mt = 0; mt < 4; ++mt)
#pragma unroll
        for (int nt = 0; nt < 4; ++nt)
          acc[mt][nt] = mfma16(af[mt], bfr[nt], acc[mt][nt]);
    }
    __syncthreads();
  }

#pragma unroll
  for (int mt = 0; mt < 4; ++mt)
#pragma unroll
    for (int nt = 0; nt < 4; ++nt)
#pragma unroll
      for (int r = 0; r < 4; ++r) {
        int row = m0 + wm * 64 + mt * 16 + l4 * 4 + r;
        int col = n0 + wn * 64 + nt * 16 + l15;
        float v = acc[mt][nt][r] + bias[col];
        if (EPI == 0) Cf[(long)row * N + col] = v;
        else          Cb[(long)row * N + col] = f2bf(v);
      }
}

// ---------- flash attention: 4 FAT waves (256 thr), QBLK=128, 32 q-rows/wave ----------
// r10 base (passing) + ONLY the fat-wave widening: K/V tiles read once per wave
// for 2 row-groups of MFMA. Mask from global (r10 path), plain launch_bounds.
__global__ __launch_bounds__(256) void attn_kernel(
    const u16* __restrict__ QKV, const u16* __restrict__ Vtg,
    const int* __restrict__ maskg, u16* __restrict__ Og)
{
  __shared__ __align__(16) u16 Ks[2][64][64];   // 16 KB
  __shared__ __align__(16) u16 Vs[2][64][64];   // 16 KB
  __shared__ __align__(16) u16 Ps[128][64];     // 16 KB  (total 48 KB)
  const int tid = threadIdx.x, lane = tid & 63, w = tid >> 6;   // w in 0..3
  const int l15 = lane & 15, l4 = lane >> 4;
  // XCD swizzle (r9-proven decode): 512 blocks -> 64/XCD, K/V set L2-resident
  const int lb = (blockIdx.x & 7) * 64 + (blockIdx.x >> 3);
  const int qt = lb & 15, bh = lb >> 4;
  const int b = bh >> 4, h = bh & 15;
  const u16* Qp = QKV + ((long)(b * SDIM + qt * 128)) * 3072 + h * 192;
  const u16* Kp = QKV + (long)(b * SDIM) * 3072 + h * 192 + 64;
  const u16* Vp = Vtg + (long)bh * HD * SDIM;
  const float SC = 0.18033688011112042f;   // log2(e) / sqrt(64)
  const int NT = SDIM / 64;                // 32

  // Q fragments: 2 row-groups of 16 rows each (rows w*32 + rt*16 + l15)
  bf16x8 qa[2][2];
#pragma unroll
  for (int rt = 0; rt < 2; ++rt)
#pragma unroll
    for (int ks = 0; ks < 2; ++ks)
      qa[rt][ks] = *(const bf16x8*)(Qp + (long)(w * 32 + rt * 16 + l15) * 3072 + ks * 32 + l4 * 8);

  f32x4 O[2][4];
  float lsum[2][4];
#pragma unroll
  for (int rt = 0; rt < 2; ++rt) {
#pragma unroll
    for (int dt = 0; dt < 4; ++dt) O[rt][dt] = {0.f, 0.f, 0.f, 0.f};
#pragma unroll
    for (int r = 0; r < 4; ++r) lsum[rt][r] = 0.f;
  }

  char* KsB = (char*)&Ks[0][0][0];
  char* VsB = (char*)&Vs[0][0][0];
  char* PsB = (char*)&Ps[0][0];
  const int srow = lane >> 3;
  const int schunk = (lane & 7) ^ srow;

  // ---- staging (byte-identical geometry to r10) ----
  // wave w stages K s-rows [w*16,+16) and V d-rows [w*16,+16), two 8-row groups
  const u16* kS0 = Kp + (long)(w * 16 + srow) * 3072 + schunk * 8;
  const u16* kS1 = Kp + (long)(w * 16 + 8 + srow) * 3072 + schunk * 8;
  const u16* vS0 = Vp + (long)(w * 16 + srow) * SDIM + schunk * 8;
  const u16* vS1 = Vp + (long)(w * 16 + 8 + srow) * SDIM + schunk * 8;
  const int* mrow = maskg + b * SDIM + l15;

  int off[2][4];     // K/V tile read offsets (row x*16+l15, chunk j*4+l4 swizzled)
#pragma unroll
  for (int j = 0; j < 2; ++j)
#pragma unroll
    for (int x = 0; x < 4; ++x)
      off[j][x] = (x * 16 + l15) * 128 + (((j * 4 + l4) ^ (l15 & 7)) << 4);
  int poffr[2][2];   // P-read (A-fragment) offsets per row-group
#pragma unroll
  for (int rt = 0; rt < 2; ++rt)
#pragma unroll
    for (int j = 0; j < 2; ++j)
      poffr[rt][j] = (w * 32 + rt * 16 + l15) * 128 + (((j * 4 + l4) ^ (l15 & 7)) << 4);
  int pw[2][4][4];   // P-write offsets per row-group
#pragma unroll
  for (int rt = 0; rt < 2; ++rt)
#pragma unroll
    for (int r = 0; r < 4; ++r) {
      int prow = w * 32 + rt * 16 + l4 * 4 + r, rx = prow & 7, ch = l15 >> 3;
      int rbase = prow * 128 + (l15 & 7) * 2;
#pragma unroll
      for (int c = 0; c < 4; ++c) pw[rt][r][c] = rbase + (((2 * c + ch) ^ rx) << 4);
    }

  // prologue: stage tile 0, advance source pointers to tile 1
  {
    u16* kd = (u16*)(KsB + w * 2048);
    u16* vd = (u16*)(VsB + w * 2048);
    gload16(kS0, kd); gload16(kS1, kd + 512);
    gload16(vS0, vd); gload16(vS1, vd + 512);
  }
  kS0 += 64 * 3072; kS1 += 64 * 3072; vS0 += 64; vS1 += 64;
  asm volatile("s_waitcnt vmcnt(0)" ::: "memory");
  __syncthreads();

  for (int kt = 0; kt < NT; ++kt) {
    const int cur = kt & 1;
    if (kt + 1 < NT) {                      // DMA next tile under compute
      u16* kd = (u16*)(KsB + (cur ^ 1) * 8192 + w * 2048);
      u16* vd = (u16*)(VsB + (cur ^ 1) * 8192 + w * 2048);
      gload16(kS0, kd); gload16(kS1, kd + 512);
      gload16(vS0, vd); gload16(vS1, vd + 512);
      kS0 += 64 * 3072; kS1 += 64 * 3072; vS0 += 64; vS1 += 64;
    }

    float mbM[4];
#pragma unroll
    for (int nt = 0; nt < 4; ++nt)
      mbM[nt] = (mrow[nt * 16] ? 0.f : -1e30f) - 12.0f;   // mask bias - static max
    mrow += 64;

    const char* Kc = KsB + cur * 8192;
    const char* Vc = VsB + cur * 8192;

    // S = Q K^T : K tile read ONCE, used by both row-groups (2x MFMA per read)
    f32x4 sc4[2][4];
    __builtin_amdgcn_s_setprio(1);
#pragma unroll
    for (int nt = 0; nt < 4; ++nt) {
      bf16x8 kb0 = *(const bf16x8*)(Kc + off[0][nt]);
      bf16x8 kb1 = *(const bf16x8*)(Kc + off[1][nt]);
#pragma unroll
      for (int rt = 0; rt < 2; ++rt) {
        f32x4 z = {0.f, 0.f, 0.f, 0.f};
        z = mfma16(qa[rt][0], kb0, z);
        z = mfma16(qa[rt][1], kb1, z);
        sc4[rt][nt] = z;
      }
    }
    __builtin_amdgcn_s_setprio(0);

    // static-max softmax: P = exp2(s*SC + mb - 12); per-lane partial row-sum
#pragma unroll
    for (int rt = 0; rt < 2; ++rt)
#pragma unroll
      for (int r = 0; r < 4; ++r) {
        float p0 = __builtin_amdgcn_exp2f(sc4[rt][0][r] * SC + mbM[0]);
        float p1 = __builtin_amdgcn_exp2f(sc4[rt][1][r] * SC + mbM[1]);
        float p2 = __builtin_amdgcn_exp2f(sc4[rt][2][r] * SC + mbM[2]);
        float p3 = __builtin_amdgcn_exp2f(sc4[rt][3][r] * SC + mbM[3]);
        lsum[rt][r] += (p0 + p1) + (p2 + p3);
        unsigned u01 = cvt_pk_bf16(p0, p1);
        unsigned u23 = cvt_pk_bf16(p2, p3);
        *(u16*)(PsB + pw[rt][r][0]) = (u16)u01;
        *(u16*)(PsB + pw[rt][r][1]) = (u16)(u01 >> 16);
        *(u16*)(PsB + pw[rt][r][2]) = (u16)u23;
        *(u16*)(PsB + pw[rt][r][3]) = (u16)(u23 >> 16);
      }
    // P consumed by the same wave only -> lgkmcnt drain, no barrier
    asm volatile("s_waitcnt lgkmcnt(0)" ::: "memory");
    __builtin_amdgcn_sched_barrier(0);

    // O += P V : V fragments read ONCE, used by both row-groups
    __builtin_amdgcn_s_setprio(1);
#pragma unroll
    for (int ks2 = 0; ks2 < 2; ++ks2) {
      bf16x8 pa0 = *(const bf16x8*)(PsB + poffr[0][ks2]);
      bf16x8 pa1 = *(const bf16x8*)(PsB + poffr[1][ks2]);
#pragma unroll
      for (int dt = 0; dt < 4; ++dt) {
        bf16x8 vb = *(const bf16x8*)(Vc + off[ks2][dt]);
        O[0][dt] = mfma16(pa0, vb, O[0][dt]);
        O[1][dt] = mfma16(pa1, vb, O[1][dt]);
      }
    }
    __builtin_amdgcn_s_setprio(0);
    __syncthreads();   // drains prefetch vmcnt + syncs buffers (one barrier per tile)
  }

  // butterflies recover each row's denominator
  float inv[2][4];
#pragma unroll
  for (int rt = 0; rt < 2; ++rt)
#pragma unroll
    for (int r = 0; r < 4; ++r) {
      float s = lsum[rt][r];
#pragma unroll
      for (int off2 = 1; off2 < 16; off2 <<= 1) s += __shfl_xor(s, off2);
      inv[rt][r] = 1.0f / s;
    }

#pragma unroll
  for (int rt = 0; rt < 2; ++rt)
#pragma unroll
    for (int dt = 0; dt < 4; ++dt)
#pragma unroll
      for (int r = 0; r < 4; ++r) {
        int s = qt * 128 + w * 32 + rt * 16 + l4 * 4 + r;
        int d = dt * 16 + l15;
        Og[((long)(b * SDIM + s)) * 1024 + h * HD + d] = f2bf(O[rt][dt][r] * inv[rt][r]);
      }
}

extern "C" void kernel_launch(void* const* d_in, const int* in_sizes, int n_in,
                              void* d_out, int out_size, void* d_ws, size_t ws_size,
                              hipStream_t stream) {
  const float* x    = (const float*)d_in[0];
  const int*   am   = (const int*)d_in[1];
  const float* Wqkv = (const float*)d_in[2];
  const float* bqkv = (const float*)d_in[3];
  const float* Wout = (const float*)d_in[4];
  const float* bout = (const float*)d_in[5];
  float* out = (float*)d_out;
  char* ws = (char*)d_ws;

  u16* xb   = (u16*)(ws);                             // 8 MB   x bf16 [4096][1024]
  u16* AOb  = (u16*)(ws);                             // reused after QKV gemm: attn out bf16
  u16* wqt  = (u16*)(ws + (size_t) 8 * 1024 * 1024);  // 6 MB   W_qkv^T bf16 [3072][1024]
  u16* wot  = (u16*)(ws + (size_t)14 * 1024 * 1024);  // 2 MB   W_out^T bf16 [1024][1024]
  u16* QKVb = (u16*)(ws + (size_t)16 * 1024 * 1024);  // 24 MB  qkv bf16 [4096][3072]
  u16* Vtb  = (u16*)(ws + (size_t)40 * 1024 * 1024);  // 8 MB   V^T bf16 [32][64][2048]

  cvt_kernel<<<2048, 256, 0, stream>>>(x, xb, 524288);
  transpose_cvt<<<dim3(96, 32), 256, 0, stream>>>(Wqkv, wqt, 1024, 3072);
  transpose_cvt<<<dim3(32, 32), 256, 0, stream>>>(Wout, wot, 1024, 1024);
  gemm_bf16<1><<<768, 256, 0, stream>>>(xb, wqt, bqkv, nullptr, QKVb,
                                        4096, 3072, 1024);
  vtrans_kernel<<<dim3(32, 32), 256, 0, stream>>>(QKVb, Vtb);
  attn_kernel<<<512, 256, 0, stream>>>(QKVb, Vtb, am, AOb);
  gemm_bf16<0><<<256, 256, 0, stream>>>(AOb, wot, bout, out, nullptr,
                                        4096, 1024, 1024);
}

// Round 13
// 139.215 us; speedup vs baseline: 1.0908x; 1.0751x over previous
//
#include <hip/hip_runtime.h>

#define SDIM 2048
#define NHEADS 16
#define HD 64

typedef __attribute__((ext_vector_type(8))) short bf16x8;
typedef __attribute__((ext_vector_type(8))) unsigned short u16x8;
typedef __attribute__((ext_vector_type(4))) float f32x4;
typedef unsigned short u16;

static __device__ __forceinline__ u16 f2bf(float f) {
  unsigned u = __builtin_bit_cast(unsigned, f);
  u += 0x7fffu + ((u >> 16) & 1u);   // RNE
  return (u16)(u >> 16);
}

// pack two f32 -> two bf16 in one instruction (no builtin on gfx950)
static __device__ __forceinline__ unsigned cvt_pk_bf16(float lo, float hi) {
  unsigned r;
  asm("v_cvt_pk_bf16_f32 %0, %1, %2" : "=v"(r) : "v"(lo), "v"(hi));
  return r;
}

static __device__ __forceinline__ f32x4 mfma16(bf16x8 a, bf16x8 b, f32x4 c) {
  return __builtin_amdgcn_mfma_f32_16x16x32_bf16(a, b, c, 0, 0, 0);
}

// async global->LDS, 16B per lane; LDS dest is wave-uniform base + lane*16
static __device__ __forceinline__ void gload16(const u16* g, u16* l) {
  __builtin_amdgcn_global_load_lds(
      (const __attribute__((address_space(1))) void*)g,
      (__attribute__((address_space(3))) void*)l, 16, 0, 0);
}

// ---------- prep: fp32 -> bf16, 8 elems/thread ----------
__global__ void cvt_kernel(const float* __restrict__ in, u16* __restrict__ out, int n8) {
  int i = blockIdx.x * blockDim.x + threadIdx.x;
  if (i >= n8) return;
  const float4* p = (const float4*)(in + (long)i * 8);
  float4 a = p[0], b = p[1];
  u16x8 r;
  r[0] = f2bf(a.x); r[1] = f2bf(a.y); r[2] = f2bf(a.z); r[3] = f2bf(a.w);
  r[4] = f2bf(b.x); r[5] = f2bf(b.y); r[6] = f2bf(b.z); r[7] = f2bf(b.w);
  *(u16x8*)(out + (long)i * 8) = r;
}

// ---------- prep: W [K][N] fp32 -> Wt [N][K] bf16 ----------
__global__ void transpose_cvt(const float* __restrict__ W, u16* __restrict__ Wt, int K, int N) {
  __shared__ float t[32][33];
  int tx = threadIdx.x & 31, ty = threadIdx.x >> 5;   // 32 x 8
  int n0 = blockIdx.x * 32, k0 = blockIdx.y * 32;
#pragma unroll
  for (int i = 0; i < 32; i += 8) t[ty + i][tx] = W[(long)(k0 + ty + i) * N + n0 + tx];
  __syncthreads();
#pragma unroll
  for (int i = 0; i < 32; i += 8) Wt[(long)(n0 + ty + i) * K + k0 + tx] = f2bf(t[tx][ty + i]);
}

// ---------- V part of QKV [4096][3072] -> Vt [32][64][2048] bf16 ----------
__global__ __launch_bounds__(256) void vtrans_kernel(const u16* __restrict__ QKV,
                                                     u16* __restrict__ Vt) {
  __shared__ u16 t[64][72];
  const int bh = blockIdx.y, s0 = blockIdx.x * 64;
  const int b = bh >> 4, h = bh & 15;
  const u16* src = QKV + ((long)(b * SDIM + s0)) * 3072 + h * 192 + 128;
  int r = threadIdx.x >> 3, c = (threadIdx.x & 7) * 8;
  *(uint4*)&t[r][c]      = *(const uint4*)(src + (long)r * 3072 + c);
  *(uint4*)&t[r + 32][c] = *(const uint4*)(src + (long)(r + 32) * 3072 + c);
  __syncthreads();
  int d = threadIdx.x >> 2, sc = (threadIdx.x & 3) * 16;
  u16 tmp[16];
#pragma unroll
  for (int k = 0; k < 16; ++k) tmp[k] = t[sc + k][d];
  u16* dst = Vt + ((long)(bh * HD + d)) * SDIM + s0 + sc;
  *(uint4*)dst = *(uint4*)&tmp[0];
  *(uint4*)(dst + 8) = *(uint4*)&tmp[8];
}

// ---------- bf16 GEMM, 128x128x64 tile, 4 waves, global_load_lds staging ----------
// Minimum 2-phase overlap: double-buffered LDS, stage(t+1) issued BEFORE compute(t),
// one vmcnt(0)+barrier per K-step. 1-D grid with bijective XCD swizzle.
template <int EPI>
__global__ __launch_bounds__(256) void gemm_bf16(
    const u16* __restrict__ A, const u16* __restrict__ Bt,
    const float* __restrict__ bias, float* __restrict__ Cf, u16* __restrict__ Cb,
    int M, int N, int K)
{
  __shared__ __align__(16) u16 As[2][128 * 64];
  __shared__ __align__(16) u16 Bs[2][128 * 64];
  const int tid = threadIdx.x, lane = tid & 63, wid = tid >> 6;
  const int wm = wid >> 1, wn = wid & 1;
  const int l15 = lane & 15, l4 = lane >> 4;
  const int nblk = gridDim.x;
  const int lb = (blockIdx.x & 7) * (nblk >> 3) + (blockIdx.x >> 3);  // XCD-chunked
  const int nx = N >> 7;
  const int m0 = (lb / nx) * 128, n0 = (lb % nx) * 128;
  const int srow = lane >> 3;
  const int schunk = (lane & 7) ^ srow;

  f32x4 acc[4][4];
#pragma unroll
  for (int i = 0; i < 4; ++i)
#pragma unroll
    for (int j = 0; j < 4; ++j) acc[i][j] = {0.f, 0.f, 0.f, 0.f};

  auto stage = [&](int kt2, int buf) {
    const int kc = kt2 << 6;
#pragma unroll
    for (int is = 0; is < 4; ++is) {
      int rb = wid * 32 + is * 8;
      int r = rb + srow;
      gload16(A  + (long)(m0 + r) * K + kc + schunk * 8, &As[buf][rb * 64]);
      gload16(Bt + (long)(n0 + r) * K + kc + schunk * 8, &Bs[buf][rb * 64]);
    }
  };

  const int nk = K >> 6;
  stage(0, 0);
  asm volatile("s_waitcnt vmcnt(0)" ::: "memory");
  __syncthreads();

  int cur = 0;
  for (int kt = 0; kt < nk; ++kt) {
    if (kt + 1 < nk) stage(kt + 1, cur ^ 1);   // overlap next-tile DMA with compute
#pragma unroll
    for (int kk = 0; kk < 2; ++kk) {
      bf16x8 af[4], bfr[4];
#pragma unroll
      for (int mt = 0; mt < 4; ++mt) {
        int row = wm * 64 + mt * 16 + l15;
        af[mt] = *(const bf16x8*)&As[cur][row * 64 + (((kk * 4 + l4) ^ (l15 & 7)) * 8)];
      }
#pragma unroll
      for (int nt = 0; nt < 4; ++nt) {
        int row = wn * 64 + nt * 16 + l15;
        bfr[nt] = *(const bf16x8*)&Bs[cur][row * 64 + (((kk * 4 + l4) ^ (l15 & 7)) * 8)];
      }
#pragma unroll
      for (int mt = 0; mt < 4; ++mt)
#pragma unroll
        for (int nt = 0; nt < 4; ++nt)
          acc[mt][nt] = mfma16(af[mt], bfr[nt], acc[mt][nt]);
    }
    asm volatile("s_waitcnt vmcnt(0)" ::: "memory");   // next-tile DMA landed
    __syncthreads();                                    // one barrier per K-step
    cur ^= 1;
  }

#pragma unroll
  for (int mt = 0; mt < 4; ++mt)
#pragma unroll
    for (int nt = 0; nt < 4; ++nt)
#pragma unroll
      for (int r = 0; r < 4; ++r) {
        int row = m0 + wm * 64 + mt * 16 + l4 * 4 + r;
        int col = n0 + wn * 64 + nt * 16 + l15;
        float v = acc[mt][nt][r] + bias[col];
        if (EPI == 0) Cf[(long)row * N + col] = v;
        else          Cb[(long)row * N + col] = f2bf(v);
      }
}

// ---------- flash attention: 8 thin waves (512 thr), QBLK=128, KBLK=64 ----------
// r9 verbatim (best measured: 63.4 us). 2-buffer, one __syncthreads per tile,
// static-max softmax, cvt_pk P, setprio, XCD swizzle, hoisted addressing.
__global__ __launch_bounds__(512) void attn_kernel(
    const u16* __restrict__ QKV, const u16* __restrict__ Vtg,
    const int* __restrict__ maskg, u16* __restrict__ Og)
{
  __shared__ __align__(16) u16 Ks[2][64][64];
  __shared__ __align__(16) u16 Vs[2][64][64];
  __shared__ __align__(16) u16 Ps[128][64];
  const int tid = threadIdx.x, lane = tid & 63, w = tid >> 6;   // w in 0..7
  const int l15 = lane & 15, l4 = lane >> 4;
  // XCD swizzle: 512 blocks -> 64/XCD = 4 heads x 16 q-tiles (K/V set 2MB < L2)
  const int lb = (blockIdx.x & 7) * 64 + (blockIdx.x >> 3);
  const int qt = lb & 15, bh = lb >> 4;
  const int b = bh >> 4, h = bh & 15;
  const u16* Qp = QKV + ((long)(b * SDIM + qt * 128)) * 3072 + h * 192;
  const u16* Kp = QKV + (long)(b * SDIM) * 3072 + h * 192 + 64;
  const u16* Vp = Vtg + (long)bh * HD * SDIM;
  const float SC = 0.18033688011112042f;   // log2(e) / sqrt(64)
  const int NT = SDIM / 64;                // 32

  bf16x8 qa[2];
#pragma unroll
  for (int ks = 0; ks < 2; ++ks)
    qa[ks] = *(const bf16x8*)(Qp + (long)(w * 16 + l15) * 3072 + ks * 32 + l4 * 8);

  f32x4 O[4];
  float lsum[4];
#pragma unroll
  for (int dt = 0; dt < 4; ++dt) O[dt] = {0.f, 0.f, 0.f, 0.f};
#pragma unroll
  for (int r = 0; r < 4; ++r) lsum[r] = 0.f;

  char* KsB = (char*)&Ks[0][0][0];
  char* VsB = (char*)&Vs[0][0][0];
  char* PsB = (char*)&Ps[0][0];
  const int srow = lane >> 3;
  const int schunk = (lane & 7) ^ srow;

  // ---- hoisted addressing (all loop-invariant) ----
  u16* kDst[2] = { (u16*)(KsB + w * 1024), (u16*)(KsB + 8192 + w * 1024) };
  u16* vDst[2] = { (u16*)(VsB + w * 1024), (u16*)(VsB + 8192 + w * 1024) };
  const u16* kS = Kp + (long)(w * 8 + srow) * 3072 + schunk * 8;   // tile 0
  const u16* vS = Vp + (long)(w * 8 + srow) * SDIM + schunk * 8;
  const int* mrow = maskg + b * SDIM + l15;

  int off[2][4];     // LDS read offsets for K and V rows (same pattern)
#pragma unroll
  for (int j = 0; j < 2; ++j)
#pragma unroll
    for (int x = 0; x < 4; ++x)
      off[j][x] = (x * 16 + l15) * 128 + (((j * 4 + l4) ^ (l15 & 7)) << 4);
  int poffr[2];      // P-read (A-fragment) offsets
#pragma unroll
  for (int j = 0; j < 2; ++j)
    poffr[j] = (w * 16 + l15) * 128 + (((j * 4 + l4) ^ (l15 & 7)) << 4);
  int pw[4][4];      // P-write offsets
#pragma unroll
  for (int r = 0; r < 4; ++r) {
    int prow = w * 16 + l4 * 4 + r, rx = prow & 7, ch = l15 >> 3;
    int rbase = prow * 128 + (l15 & 7) * 2;
#pragma unroll
    for (int c = 0; c < 4; ++c) pw[r][c] = rbase + (((2 * c + ch) ^ rx) << 4);
  }

  // prologue: stage tile 0, advance source pointers to tile 1
  gload16(kS, kDst[0]); gload16(vS, vDst[0]);
  kS += 64 * 3072; vS += 64;
  asm volatile("s_waitcnt vmcnt(0)" ::: "memory");
  __syncthreads();

  for (int kt = 0; kt < NT; ++kt) {
    const int cur = kt & 1;
    if (kt + 1 < NT) {                      // DMA next tile under compute
      gload16(kS, kDst[cur ^ 1]); gload16(vS, vDst[cur ^ 1]);
      kS += 64 * 3072; vS += 64;
    }

    float mbM[4];
#pragma unroll
    for (int nt = 0; nt < 4; ++nt)
      mbM[nt] = (mrow[nt * 16] ? 0.f : -1e30f) - 12.0f;   // mask bias - static max
    mrow += 64;

    const char* Kc = KsB + cur * 8192;
    const char* Vc = VsB + cur * 8192;

    // S = Q K^T (per wave: 16 x 64)
    f32x4 sc4[4];
    __builtin_amdgcn_s_setprio(1);
#pragma unroll
    for (int nt = 0; nt < 4; ++nt) {
      bf16x8 kb0 = *(const bf16x8*)(Kc + off[0][nt]);
      bf16x8 kb1 = *(const bf16x8*)(Kc + off[1][nt]);
      f32x4 z = {0.f, 0.f, 0.f, 0.f};
      z = mfma16(qa[0], kb0, z);
      z = mfma16(qa[1], kb1, z);
      sc4[nt] = z;
    }
    __builtin_amdgcn_s_setprio(0);

    // static-max softmax: P = exp2(s*SC + mb - 12); per-lane partial row-sum
#pragma unroll
    for (int r = 0; r < 4; ++r) {
      float p0 = __builtin_amdgcn_exp2f(sc4[0][r] * SC + mbM[0]);
      float p1 = __builtin_amdgcn_exp2f(sc4[1][r] * SC + mbM[1]);
      float p2 = __builtin_amdgcn_exp2f(sc4[2][r] * SC + mbM[2]);
      float p3 = __builtin_amdgcn_exp2f(sc4[3][r] * SC + mbM[3]);
      lsum[r] += (p0 + p1) + (p2 + p3);
      unsigned u01 = cvt_pk_bf16(p0, p1);
      unsigned u23 = cvt_pk_bf16(p2, p3);
      *(u16*)(PsB + pw[r][0]) = (u16)u01;
      *(u16*)(PsB + pw[r][1]) = (u16)(u01 >> 16);
      *(u16*)(PsB + pw[r][2]) = (u16)u23;
      *(u16*)(PsB + pw[r][3]) = (u16)(u23 >> 16);
    }
    // P consumed by the same wave only -> lgkmcnt drain, no barrier
    asm volatile("s_waitcnt lgkmcnt(0)" ::: "memory");
    __builtin_amdgcn_sched_barrier(0);

    // O += P V
    __builtin_amdgcn_s_setprio(1);
#pragma unroll
    for (int ks2 = 0; ks2 < 2; ++ks2) {
      bf16x8 pa = *(const bf16x8*)(PsB + poffr[ks2]);
#pragma unroll
      for (int dt = 0; dt < 4; ++dt) {
        bf16x8 vb = *(const bf16x8*)(Vc + off[ks2][dt]);
        O[dt] = mfma16(pa, vb, O[dt]);
      }
    }
    __builtin_amdgcn_s_setprio(0);
    __syncthreads();   // drains prefetch vmcnt + syncs buffers (one barrier per tile)
  }

  // one butterfly at the end recovers each row's denominator
  float inv[4];
#pragma unroll
  for (int r = 0; r < 4; ++r) {
    float s = lsum[r];
#pragma unroll
    for (int off2 = 1; off2 < 16; off2 <<= 1) s += __shfl_xor(s, off2);
    inv[r] = 1.0f / s;
  }

#pragma unroll
  for (int dt = 0; dt < 4; ++dt)
#pragma unroll
    for (int r = 0; r < 4; ++r) {
      int s = qt * 128 + w * 16 + l4 * 4 + r;
      int d = dt * 16 + l15;
      Og[((long)(b * SDIM + s)) * 1024 + h * HD + d] = f2bf(O[dt][r] * inv[r]);
    }
}

extern "C" void kernel_launch(void* const* d_in, const int* in_sizes, int n_in,
                              void* d_out, int out_size, void* d_ws, size_t ws_size,
                              hipStream_t stream) {
  const float* x    = (const float*)d_in[0];
  const int*   am   = (const int*)d_in[1];
  const float* Wqkv = (const float*)d_in[2];
  const float* bqkv = (const float*)d_in[3];
  const float* Wout = (const float*)d_in[4];
  const float* bout = (const float*)d_in[5];
  float* out = (float*)d_out;
  char* ws = (char*)d_ws;

  u16* xb   = (u16*)(ws);                             // 8 MB   x bf16 [4096][1024]
  u16* AOb  = (u16*)(ws);                             // reused after QKV gemm: attn out bf16
  u16* wqt  = (u16*)(ws + (size_t) 8 * 1024 * 1024);  // 6 MB   W_qkv^T bf16 [3072][1024]
  u16* wot  = (u16*)(ws + (size_t)14 * 1024 * 1024);  // 2 MB   W_out^T bf16 [1024][1024]
  u16* QKVb = (u16*)(ws + (size_t)16 * 1024 * 1024);  // 24 MB  qkv bf16 [4096][3072]
  u16* Vtb  = (u16*)(ws + (size_t)40 * 1024 * 1024);  // 8 MB   V^T bf16 [32][64][2048]

  cvt_kernel<<<2048, 256, 0, stream>>>(x, xb, 524288);
  transpose_cvt<<<dim3(96, 32), 256, 0, stream>>>(Wqkv, wqt, 1024, 3072);
  transpose_cvt<<<dim3(32, 32), 256, 0, stream>>>(Wout, wot, 1024, 1024);
  gemm_bf16<1><<<768, 256, 0, stream>>>(xb, wqt, bqkv, nullptr, QKVb,
                                        4096, 3072, 1024);
  vtrans_kernel<<<dim3(32, 32), 256, 0, stream>>>(QKVb, Vtb);
  attn_kernel<<<512, 512, 0, stream>>>(QKVb, Vtb, am, AOb);
  gemm_bf16<0><<<256, 256, 0, stream>>>(AOb, wot, bout, out, nullptr,
                                        4096, 1024, 1024);
}